// Round 5
// baseline (422.876 us; speedup 1.0000x reference)
//
#include <hip/hip_runtime.h>
#include <math.h>

// Router: x[8192,4096] fp32; Wg,Wc[64,4096]; scores=|cls*silu(gate)|, softmax,
// top-8 of scores+bias, weights = 1 + scores*extra_scale (gathered).
// Out: weights [8192,8] fp32, then indices [8192,8] written as float values.
//
// R5: 6-term 3-way-split bf16 MFMA GEMM (x=h+m+l, W=H+M+L; products kept down
// to 2^-18: hH,hM,mH,hL,mM,lH -> dot noise ~1e-7) + per-row top-9 margin test
// in the topk kernel with an exact-fp32 fallback for rows whose min rank gap
// < 2e-6. R4's 3-term (noise ~1e-5) flipped a handful of indices; the margin
// test makes correctness independent of the noise estimate.

#define T_DIM 8192
#define D_DIM 4096
#define E_DIM 64
#define N2    128      // 64 gate cols + 64 cls cols
#define MB    128      // rows per WG (4 waves x 32 rows)
#define KTOP  8
#define GAP_THRESH 2e-6f

typedef __bf16 bf16x8 __attribute__((ext_vector_type(8)));
typedef __bf16 bf16x4 __attribute__((ext_vector_type(4)));
typedef float  f32x4  __attribute__((ext_vector_type(4)));

// ---------------- Kernel 0: split W (gate||cls) into 3 bf16 planes ----------
__global__ __launch_bounds__(256)
void wsplit(const float* __restrict__ Wg, const float* __restrict__ Wc,
            __bf16* __restrict__ WH, __bf16* __restrict__ WM,
            __bf16* __restrict__ WL)
{
    const size_t i    = ((size_t)blockIdx.x * 256 + threadIdx.x) * 4;
    const size_t half = (size_t)E_DIM * D_DIM;   // 262144
    const float4 v = (i < half) ? ((const float4*)Wg)[i >> 2]
                                : ((const float4*)Wc)[(i - half) >> 2];
    const float f[4] = {v.x, v.y, v.z, v.w};
    bf16x4 hv, mv, lv;
    #pragma unroll
    for (int j = 0; j < 4; ++j) {
        const __bf16 h = (__bf16)f[j];           // RNE
        const float r1 = f[j] - (float)h;
        const __bf16 m = (__bf16)r1;
        const float r2 = r1 - (float)m;
        hv[j] = h; mv[j] = m; lv[j] = (__bf16)r2;
    }
    *(bf16x4*)(WH + i) = hv;
    *(bf16x4*)(WM + i) = mv;
    *(bf16x4*)(WL + i) = lv;
}

// ---------------- Kernel 1: 6-term split-bf16 MFMA GEMM ---------------------
__device__ __forceinline__ void split3_8(const float4 a, const float4 b,
                                         bf16x8& h, bf16x8& m, bf16x8& l)
{
    const float f[8] = {a.x, a.y, a.z, a.w, b.x, b.y, b.z, b.w};
    #pragma unroll
    for (int j = 0; j < 8; ++j) {
        const __bf16 hj = (__bf16)f[j];
        const float r1 = f[j] - (float)hj;
        const __bf16 mj = (__bf16)r1;
        const float r2 = r1 - (float)mj;
        h[j] = hj; m[j] = mj; l[j] = (__bf16)r2;
    }
}

template<int KS>
__global__ __launch_bounds__(256)
void router_gemm(const float* __restrict__ x,
                 const __bf16* __restrict__ WH,
                 const __bf16* __restrict__ WM,
                 const __bf16* __restrict__ WL,
                 float* __restrict__ P)
{
    constexpr int SLICEK = D_DIM / KS;
    constexpr int NSTEP  = SLICEK / 32;      // k32 steps per slice

    const int lane = threadIdx.x & 63;
    const int wid  = threadIdx.x >> 6;
    const int mb   = blockIdx.x;
    const int ks   = blockIdx.y;

    const int m0   = mb * MB + wid * 32;     // this wave: rows m0..m0+31
    const int mrow = lane & 15;              // A row / B col within subtile
    const int quad = lane >> 4;              // k-quad: k = quad*8 + j
    const int k0   = ks * SLICEK + quad * 8;

    const float* xa0 = x + (size_t)(m0 +      mrow) * D_DIM + k0;
    const float* xa1 = x + (size_t)(m0 + 16 + mrow) * D_DIM + k0;
    const size_t bofs = (size_t)mrow * D_DIM + k0;   // W row-major == B^T

    f32x4 acc[2][8];
    #pragma unroll
    for (int mt = 0; mt < 2; ++mt)
        #pragma unroll
        for (int nt = 0; nt < 8; ++nt)
            acc[mt][nt] = (f32x4){0.f, 0.f, 0.f, 0.f};

    float4 p00 = *(const float4*)(xa0);
    float4 p01 = *(const float4*)(xa0 + 4);
    float4 p10 = *(const float4*)(xa1);
    float4 p11 = *(const float4*)(xa1 + 4);

    for (int s = 0; s < NSTEP; ++s) {
        bf16x8 a0h, a0m, a0l, a1h, a1m, a1l;
        split3_8(p00, p01, a0h, a0m, a0l);
        split3_8(p10, p11, a1h, a1m, a1l);

        if (s + 1 < NSTEP) {                  // prefetch next x fragment
            const int kn = (s + 1) * 32;
            p00 = *(const float4*)(xa0 + kn);
            p01 = *(const float4*)(xa0 + kn + 4);
            p10 = *(const float4*)(xa1 + kn);
            p11 = *(const float4*)(xa1 + kn + 4);
        }

        const int kk = s * 32;
        #pragma unroll
        for (int nt = 0; nt < 8; ++nt) {
            const size_t bo = bofs + (size_t)nt * 16 * D_DIM + kk;
            const bf16x8 BH = *(const bf16x8*)(WH + bo);
            const bf16x8 BM = *(const bf16x8*)(WM + bo);
            const bf16x8 BL = *(const bf16x8*)(WL + bo);
            // terms down to 2^-18: hH, hM, mH, hL, mM, lH
            acc[0][nt] = __builtin_amdgcn_mfma_f32_16x16x32_bf16(a0h, BH, acc[0][nt], 0, 0, 0);
            acc[0][nt] = __builtin_amdgcn_mfma_f32_16x16x32_bf16(a0h, BM, acc[0][nt], 0, 0, 0);
            acc[0][nt] = __builtin_amdgcn_mfma_f32_16x16x32_bf16(a0m, BH, acc[0][nt], 0, 0, 0);
            acc[0][nt] = __builtin_amdgcn_mfma_f32_16x16x32_bf16(a0h, BL, acc[0][nt], 0, 0, 0);
            acc[0][nt] = __builtin_amdgcn_mfma_f32_16x16x32_bf16(a0m, BM, acc[0][nt], 0, 0, 0);
            acc[0][nt] = __builtin_amdgcn_mfma_f32_16x16x32_bf16(a0l, BH, acc[0][nt], 0, 0, 0);
            acc[1][nt] = __builtin_amdgcn_mfma_f32_16x16x32_bf16(a1h, BH, acc[1][nt], 0, 0, 0);
            acc[1][nt] = __builtin_amdgcn_mfma_f32_16x16x32_bf16(a1h, BM, acc[1][nt], 0, 0, 0);
            acc[1][nt] = __builtin_amdgcn_mfma_f32_16x16x32_bf16(a1m, BH, acc[1][nt], 0, 0, 0);
            acc[1][nt] = __builtin_amdgcn_mfma_f32_16x16x32_bf16(a1h, BL, acc[1][nt], 0, 0, 0);
            acc[1][nt] = __builtin_amdgcn_mfma_f32_16x16x32_bf16(a1m, BM, acc[1][nt], 0, 0, 0);
            acc[1][nt] = __builtin_amdgcn_mfma_f32_16x16x32_bf16(a1l, BH, acc[1][nt], 0, 0, 0);
        }
    }

    // C/D layout (m89/m91): col = lane&15, row = (lane>>4)*4 + reg
    #pragma unroll
    for (int mt = 0; mt < 2; ++mt)
        #pragma unroll
        for (int nt = 0; nt < 8; ++nt) {
            float* Pp = P + ((size_t)ks * T_DIM + m0 + mt * 16 + quad * 4) * N2
                          + nt * 16 + mrow;
            #pragma unroll
            for (int r = 0; r < 4; ++r)
                Pp[(size_t)r * N2] = acc[mt][nt][r];
        }
}

// -------- Kernel 2: reduce + softmax + top-8 with margin + exact fallback ---
template<int KS>
__global__ __launch_bounds__(256)
void router_topk(const float* __restrict__ P,
                 const float* __restrict__ scale,
                 const float* __restrict__ bias,
                 const float* __restrict__ x,
                 const float* __restrict__ Wg,
                 const float* __restrict__ Wc,
                 float* __restrict__ out)
{
    const int lane = threadIdx.x & 63;   // expert id
    const int wid  = threadIdx.x >> 6;
    const int row  = blockIdx.x * 4 + wid;

    float gv[KS], cv[KS];
    #pragma unroll
    for (int ks = 0; ks < KS; ++ks) {
        const float* p = P + ((size_t)ks * T_DIM + row) * N2;
        gv[ks] = p[lane];
        cv[ks] = p[E_DIM + lane];
    }
    float g = 0.f, c = 0.f;
    #pragma unroll
    for (int ks = 0; ks < KS; ++ks) { g += gv[ks]; c += cv[ks]; }

    const float sc  = scale[lane];
    const float bsv = bias[lane];

    // --- approx scores -> softmax -> biased ---
    float sg = g / (1.f + expf(-g));
    float v  = fabsf(c * sg);
    float m = v;
    #pragma unroll
    for (int off = 32; off >= 1; off >>= 1) m = fmaxf(m, __shfl_xor(m, off));
    float e = expf(v - m);
    float Z = e;
    #pragma unroll
    for (int off = 32; off >= 1; off >>= 1) Z += __shfl_xor(Z, off);
    float s = e / Z;
    float cur = s + bsv;

    // --- top-8 selection, tracking min gap among ranks 1..9 ---
    float myw = 0.f; int myi = 0;
    float prev = 0.f, mingap = 1e30f;
    #pragma unroll
    for (int j = 0; j < KTOP + 1; ++j) {
        float bv = cur; int bi = lane;
        #pragma unroll
        for (int off = 32; off >= 1; off >>= 1) {
            const float ov = __shfl_xor(bv, off);
            const int   oi = __shfl_xor(bi, off);
            if (ov > bv || (ov == bv && oi < bi)) { bv = ov; bi = oi; }
        }
        if (j > 0) mingap = fminf(mingap, prev - bv);
        prev = bv;
        if (j < KTOP) {
            const float s_bi  = __shfl(s,  bi);
            const float sc_bi = __shfl(sc, bi);
            if (lane == j)  { myw = 1.f + s_bi * sc_bi; myi = bi; }
            if (lane == bi) cur = -INFINITY;
        }
    }

    // --- exact fp32 fallback when ranking is not provably stable ---
    if (mingap < GAP_THRESH) {               // wave-uniform (butterfly result)
        const float* xr = x  + (size_t)row  * D_DIM;
        const float* wg = Wg + (size_t)lane * D_DIM;
        const float* wc = Wc + (size_t)lane * D_DIM;
        float g0 = 0.f, g1 = 0.f, c0 = 0.f, c1 = 0.f;
        #pragma unroll 4
        for (int k = 0; k < D_DIM; k += 8) {
            const float4 xv0 = *(const float4*)(xr + k);
            const float4 xv1 = *(const float4*)(xr + k + 4);
            const float4 wg0 = *(const float4*)(wg + k);
            const float4 wg1 = *(const float4*)(wg + k + 4);
            const float4 wc0 = *(const float4*)(wc + k);
            const float4 wc1 = *(const float4*)(wc + k + 4);
            g0 = fmaf(xv0.x, wg0.x, fmaf(xv0.y, wg0.y, fmaf(xv0.z, wg0.z, fmaf(xv0.w, wg0.w, g0))));
            g1 = fmaf(xv1.x, wg1.x, fmaf(xv1.y, wg1.y, fmaf(xv1.z, wg1.z, fmaf(xv1.w, wg1.w, g1))));
            c0 = fmaf(xv0.x, wc0.x, fmaf(xv0.y, wc0.y, fmaf(xv0.z, wc0.z, fmaf(xv0.w, wc0.w, c0))));
            c1 = fmaf(xv1.x, wc1.x, fmaf(xv1.y, wc1.y, fmaf(xv1.z, wc1.z, fmaf(xv1.w, wc1.w, c1))));
        }
        const float ge = g0 + g1, ce = c0 + c1;
        sg = ge / (1.f + expf(-ge));
        v  = fabsf(ce * sg);
        m = v;
        #pragma unroll
        for (int off = 32; off >= 1; off >>= 1) m = fmaxf(m, __shfl_xor(m, off));
        e = expf(v - m);
        Z = e;
        #pragma unroll
        for (int off = 32; off >= 1; off >>= 1) Z += __shfl_xor(Z, off);
        s = e / Z;
        cur = s + bsv;
        #pragma unroll
        for (int j = 0; j < KTOP; ++j) {
            float bv = cur; int bi = lane;
            #pragma unroll
            for (int off = 32; off >= 1; off >>= 1) {
                const float ov = __shfl_xor(bv, off);
                const int   oi = __shfl_xor(bi, off);
                if (ov > bv || (ov == bv && oi < bi)) { bv = ov; bi = oi; }
            }
            const float s_bi  = __shfl(s,  bi);
            const float sc_bi = __shfl(sc, bi);
            if (lane == j)  { myw = 1.f + s_bi * sc_bi; myi = bi; }
            if (lane == bi) cur = -INFINITY;
        }
    }

    if (lane < KTOP) {
        out[(size_t)row * KTOP + lane] = myw;
        out[(size_t)T_DIM * KTOP + (size_t)row * KTOP + lane] = (float)myi;
    }
}

template<int KS>
static void launch_all(const float* x, const float* Wg, const float* Wc,
                       const float* sc, const float* bs,
                       float* out, void* ws, hipStream_t stream)
{
    __bf16* WH = (__bf16*)ws;
    __bf16* WM = WH + (size_t)N2 * D_DIM;
    __bf16* WL = WM + (size_t)N2 * D_DIM;
    float*  P  = (float*)(WL + (size_t)N2 * D_DIM);

    wsplit<<<(N2 * D_DIM) / (256 * 4), 256, 0, stream>>>(Wg, Wc, WH, WM, WL);
    router_gemm<KS><<<dim3(T_DIM / MB, KS), 256, 0, stream>>>(x, WH, WM, WL, P);
    router_topk<KS><<<T_DIM / 4, 256, 0, stream>>>(P, sc, bs, x, Wg, Wc, out);
}

extern "C" void kernel_launch(void* const* d_in, const int* in_sizes, int n_in,
                              void* d_out, int out_size, void* d_ws, size_t ws_size,
                              hipStream_t stream)
{
    const float* x  = (const float*)d_in[0];
    const float* Wg = (const float*)d_in[1];
    const float* Wc = (const float*)d_in[2];
    const float* sc = (const float*)d_in[3];
    const float* bs = (const float*)d_in[4];
    float* out = (float*)d_out;

    // ws: WH|WM|WL (3 MB) | P (ksplit * 4 MB)
    const size_t wfix = (size_t)3 * N2 * D_DIM * sizeof(__bf16);
    const size_t per  = (size_t)T_DIM * N2 * sizeof(float);
    int ksplit = 8;
    while (ksplit > 1 && wfix + (size_t)ksplit * per > ws_size) ksplit >>= 1;

    switch (ksplit) {
        case 8:  launch_all<8>(x, Wg, Wc, sc, bs, out, d_ws, stream); break;
        case 4:  launch_all<4>(x, Wg, Wc, sc, bs, out, d_ws, stream); break;
        case 2:  launch_all<2>(x, Wg, Wc, sc, bs, out, d_ws, stream); break;
        default: launch_all<1>(x, Wg, Wc, sc, bs, out, d_ws, stream); break;
    }
}